// Round 4
// baseline (226.391 us; speedup 1.0000x reference)
//
#include <hip/hip_runtime.h>
#include <cmath>

namespace {
constexpr float kE   = 3130.0f;
constexpr float kNu  = 0.37f;
constexpr float kSy0 = 64.8f;
constexpr float kH   = 100.0f;
constexpr float kG   = kE / (2.0f * (1.0f + kNu));
constexpr float kLam = kE * kNu / ((1.0f + kNu) * (1.0f - 2.0f * kNu));
constexpr float kC   = kE / ((1.0f + kNu) * (1.0f - 2.0f * kNu));
constexpr float kC11 = kC * (1.0f - kNu);
constexpr float kC12 = kC * kNu;
constexpr float kC2  = 3.0f * kG / (3.0f * kG + kH);  // 3G/(3G+H)
constexpr float kC3  = kH / (3.0f * kG + kH);         // 1 - kC2
constexpr int kS  = 2048;
constexpr int kT  = 16;
constexpr int kNB = kS / kT;   // 128 blocks
constexpr int kLs = 192;
constexpr float kSq15  = 1.224744871391589f;  // sqrt(1.5)
constexpr float kSq3   = 1.732050807568877f;  // sqrt(3)
constexpr float kISq15 = 1.0f / kSq15;
constexpr float kISq3  = 1.0f / kSq3;
}

template<int CTRL, int RM, int BM>
__device__ __forceinline__ float dppmov(float v) {
    return __int_as_float(
        __builtin_amdgcn_update_dpp(0, __float_as_int(v), CTRL, RM, BM, false));
}
// wave64 sum, result in lane 63
__device__ __forceinline__ float wave_sum63(float v) {
    v += dppmov<0x111, 0xf, 0xf>(v);
    v += dppmov<0x112, 0xf, 0xf>(v);
    v += dppmov<0x114, 0xf, 0xf>(v);
    v += dppmov<0x118, 0xf, 0xf>(v);
    v += dppmov<0x142, 0xa, 0xf>(v);
    v += dppmov<0x143, 0xc, 0xf>(v);
    return v;
}

// Barrier WITHOUT the implicit vmcnt(0) drain of __syncthreads():
// LDS producers must be complete (lgkmcnt) but global loads/stores stay in
// flight across phases — the compiler inserts counted vmcnt waits at uses.
__device__ __forceinline__ void phase_barrier() {
    asm volatile("s_waitcnt lgkmcnt(0)" ::: "memory");
    __builtin_amdgcn_s_barrier();
    asm volatile("" ::: "memory");
}

// 5 waves: w0 = deviatoric scan; w1,w2 = strain projection (half-blocks);
// w3,w4 = output einsum + DPP reduce + store (half-blocks).
// Mean stress p(t) = mv . x(t) is purely elastic -> handled by out-waves.
__global__ __launch_bounds__(320, 1)
void j2_pc5_kernel(const float* __restrict__ x,
                   const float* __restrict__ W1,
                   const float* __restrict__ W2,
                   float* __restrict__ out)
{
    __shared__ float4 ubuf[2][kT][64];   // (du0, du1, dush, duz), sqrt-folded
    __shared__ float4 sgbuf[2][kT][64];  // (s0, s1, s2, -) post-fac deviatoric

    const int b = blockIdx.x;
    const int w = threadIdx.x >> 6;   // 0..4
    const int k = threadIdx.x & 63;

    const float* xb = x + (size_t)b * (kS * 3);
    float* ob = out + (size_t)b * (kS * 3);

    // ---- per-role constants -------------------------------------------------
    float e0[3], e1[3], e2s[3], lv[3];   // u-prod rows (e2s: sqrt3*G folded)
    float spp[3][3], so[3], mv[3];       // out-wave weights
    if (w >= 1) {
        float wr[3][3];
#pragma unroll
        for (int j = 0; j < 3; ++j)
#pragma unroll
            for (int f = 0; f < 3; ++f)
                wr[j][f] = W1[(3 * k + j) * 3 + f];
#pragma unroll
        for (int f = 0; f < 3; ++f) {
            e0[f]  = kC11 * wr[0][f] + kC12 * wr[1][f];
            e1[f]  = kC12 * wr[0][f] + kC11 * wr[1][f];
            e2s[f] = kSq3 * kG * wr[2][f];
            lv[f]  = kLam * (wr[0][f] + wr[1][f]);
            mv[f]  = (e0[f] + e1[f] + lv[f]) * (1.0f / 3.0f);
        }
#pragma unroll
        for (int o = 0; o < 3; ++o) {
            float a0 = log1pf(expf(W2[o * kLs + 3 * k + 0]));
            float a1 = log1pf(expf(W2[o * kLs + 3 * k + 1]));
            float a2 = log1pf(expf(W2[o * kLs + 3 * k + 2]));
            spp[o][0] = a0 * kISq15;
            spp[o][1] = a1 * kISq15;
            spp[o][2] = a2 * kISq3;
            so[o] = a0 + a1;
        }
    }

    // ---- u-prod x-register pipeline (block 0 prologue) ---------------------
    float xv[28];
    if (w == 1) {
        xv[0] = xv[1] = xv[2] = xv[3] = 0.f;      // x_{-1} = 0
        const float4* s4 = reinterpret_cast<const float4*>(xb);
#pragma unroll
        for (int i = 0; i < 6; ++i) {
            float4 v = s4[i];
            xv[4 + 4 * i] = v.x; xv[5 + 4 * i] = v.y;
            xv[6 + 4 * i] = v.z; xv[7 + 4 * i] = v.w;
        }
    } else if (w == 2) {
        const float4* s4 = reinterpret_cast<const float4*>(xb + 20);
#pragma unroll
        for (int i = 0; i < 7; ++i) {
            float4 v = s4[i];
            xv[4 * i]     = v.x; xv[4 * i + 1] = v.y;
            xv[4 * i + 2] = v.z; xv[4 * i + 3] = v.w;
        }
    }

    // ---- out-wave x pipeline (mean-stress term), one phase ahead -----------
    float xq[24];
    if (w >= 3) {
        const int tbase = (w == 4) ? 8 : 0;
        const float4* s4 = reinterpret_cast<const float4*>(xb + tbase * 3);
#pragma unroll
        for (int i = 0; i < 6; ++i) {
            float4 v = s4[i];
            xq[4 * i]     = v.x; xq[4 * i + 1] = v.y;
            xq[4 * i + 2] = v.z; xq[4 * i + 3] = v.w;
        }
    }

    // ---- scan state ---------------------------------------------------------
    float s0 = 0.f, s1 = 0.f, s2 = 0.f, sz = 0.f;
    float y = kSy0, c2y = kC2 * kSy0;

    // phase p: w1/w2 produce ubuf[block p]; w0 scans block p-1;
    //          w3/w4 emit output for block p-2.
    for (int phase = 0; phase <= kNB + 1; ++phase) {
        if (w == 0) {
            if (phase >= 1 && phase <= kNB) {
                const int blk = phase - 1, rb = blk & 1;
                float4 u[kT];
#pragma unroll
                for (int t = 0; t < kT; ++t) u[t] = ubuf[rb][t][k];
#pragma unroll
                for (int t = 0; t < kT; ++t) {
                    const float s0t = s0 + u[t].x;
                    const float s1t = s1 + u[t].y;
                    const float s2t = s2 + u[t].z;
                    const float szt = sz + u[t].w;
                    const float q2 = fmaf(s0t, s0t, fmaf(s1t, s1t, 1e-12f))
                                   + fmaf(s2t, s2t, szt * szt);
                    const float rq  = __builtin_amdgcn_rsqf(q2);
                    const float fac = fminf(fmaf(c2y, rq, kC3), 1.0f);
                    s0 = fac * s0t; s1 = fac * s1t;
                    s2 = fac * s2t; sz = fac * szt;
                    const float qv = q2 * rq;                 // ~|s_tr|
                    y = fmaf(kC3, fmaxf(qv - y, 0.0f), y);
                    c2y = kC2 * y;
                    sgbuf[rb][t][k] = make_float4(s0, s1, s2, 0.f);
                }
            }
        } else if (w <= 2) {
            if (phase < kNB) {
                const int p = phase, pb = p & 1;
                float xn[28];
                const bool pref = (p + 1 < kNB);
                if (pref) {   // issue next block's window loads (span barrier)
                    const float4* s4 = reinterpret_cast<const float4*>(
                        xb + (p + 1) * 48 + ((w == 1) ? -4 : 20));
#pragma unroll
                    for (int i = 0; i < 7; ++i) {
                        float4 v = s4[i];
                        xn[4 * i]     = v.x; xn[4 * i + 1] = v.y;
                        xn[4 * i + 2] = v.z; xn[4 * i + 3] = v.w;
                    }
                }
                const int tbase = (w == 2) ? 8 : 0;
#pragma unroll
                for (int t = 0; t < 8; ++t) {
                    const float dx0 = xv[3 * t + 4] - xv[3 * t + 1];
                    const float dx1 = xv[3 * t + 5] - xv[3 * t + 2];
                    const float dx2 = xv[3 * t + 6] - xv[3 * t + 3];
                    const float ux  = fmaf(e0[0], dx0, fmaf(e0[1], dx1, e0[2] * dx2));
                    const float uy  = fmaf(e1[0], dx0, fmaf(e1[1], dx1, e1[2] * dx2));
                    const float ush = fmaf(e2s[0], dx0, fmaf(e2s[1], dx1, e2s[2] * dx2));
                    const float uzl = fmaf(lv[0], dx0, fmaf(lv[1], dx1, lv[2] * dx2));
                    const float um  = (ux + uy + uzl) * (1.0f / 3.0f);
                    ubuf[pb][tbase + t][k] =
                        make_float4(kSq15 * (ux - um), kSq15 * (uy - um),
                                    ush, kSq15 * (uzl - um));
                }
                if (pref) {
#pragma unroll
                    for (int i = 0; i < 28; ++i) xv[i] = xn[i];
                }
            }
        } else {
            if (phase >= 2) {
                const int q = phase - 2, qb = q & 1;
                const int tbase = (w == 4) ? 8 : 0;
                float r[24];
#pragma unroll
                for (int t = 0; t < 8; ++t) {
                    float4 s = sgbuf[qb][tbase + t][k];
                    const float pm = fmaf(mv[0], xq[3 * t + 0],
                                     fmaf(mv[1], xq[3 * t + 1],
                                          mv[2] * xq[3 * t + 2]));
#pragma unroll
                    for (int o = 0; o < 3; ++o) {
                        const float A = fmaf(spp[o][0], s.x,
                                        fmaf(spp[o][1], s.y, spp[o][2] * s.z));
                        r[3 * t + o] = fmaf(pm, so[o], A);
                    }
                }
                // xq dead -> issue next block's loads now; they complete
                // under the DPP reduce + barrier (no vmcnt drain anymore).
                if (q + 1 < kNB) {
                    const float4* s4 = reinterpret_cast<const float4*>(
                        xb + (q + 1) * 48 + tbase * 3);
#pragma unroll
                    for (int i = 0; i < 6; ++i) {
                        float4 v = s4[i];
                        xq[4 * i]     = v.x; xq[4 * i + 1] = v.y;
                        xq[4 * i + 2] = v.z; xq[4 * i + 3] = v.w;
                    }
                }
#pragma unroll
                for (int v = 0; v < 24; ++v) r[v] = wave_sum63(r[v]);
                if (k == 63) {
                    float4* o4 = reinterpret_cast<float4*>(ob + q * 48 + tbase * 3);
#pragma unroll
                    for (int i = 0; i < 6; ++i)
                        o4[i] = make_float4(r[4 * i], r[4 * i + 1],
                                            r[4 * i + 2], r[4 * i + 3]);
                }
            }
        }
        phase_barrier();
    }
}

extern "C" void kernel_launch(void* const* d_in, const int* in_sizes, int n_in,
                              void* d_out, int out_size, void* d_ws, size_t ws_size,
                              hipStream_t stream) {
    const float* x  = (const float*)d_in[0];   // (128, 2048, 3)
    const float* W1 = (const float*)d_in[1];   // (192, 3)
    const float* W2 = (const float*)d_in[2];   // (3, 192)
    float* out = (float*)d_out;                // (128, 2048, 3)

    j2_pc5_kernel<<<dim3(128), dim3(320), 0, stream>>>(x, W1, W2, out);
}

// Round 7
// 169.262 us; speedup vs baseline: 1.3375x; 1.3375x over previous
//
#include <hip/hip_runtime.h>
#include <cmath>

namespace {
constexpr float kE   = 3130.0f;
constexpr float kNu  = 0.37f;
constexpr float kSy0 = 64.8f;
constexpr float kH   = 100.0f;
constexpr float kG   = kE / (2.0f * (1.0f + kNu));
constexpr float kLam = kE * kNu / ((1.0f + kNu) * (1.0f - 2.0f * kNu));
constexpr float kC   = kE / ((1.0f + kNu) * (1.0f - 2.0f * kNu));
constexpr float kC11 = kC * (1.0f - kNu);
constexpr float kC12 = kC * kNu;
constexpr float kC2  = 3.0f * kG / (3.0f * kG + kH);  // 3G/(3G+H)
constexpr float kC3  = kH / (3.0f * kG + kH);         // 1 - kC2
constexpr int kS  = 2048;
constexpr int kT  = 16;
constexpr int kNBLK = kS / kT;   // 128
constexpr int kLs = 192;
constexpr float kSq15  = 1.224744871391589f;  // sqrt(1.5)
constexpr float kSq3   = 1.732050807568877f;  // sqrt(3)
constexpr float kISq15 = 1.0f / kSq15;
constexpr float kISq3  = 1.0f / kSq3;
}

typedef __fp16 half2_t __attribute__((ext_vector_type(2)));

__device__ __forceinline__ unsigned pk16(float a, float b) {
    half2_t h = __builtin_amdgcn_cvt_pkrtz(a, b);
    return __builtin_bit_cast(unsigned, h);
}
__device__ __forceinline__ float up16lo(unsigned u) {
    half2_t h = __builtin_bit_cast(half2_t, u);
    return (float)h.x;
}
__device__ __forceinline__ float up16hi(unsigned u) {
    half2_t h = __builtin_bit_cast(half2_t, u);
    return (float)h.y;
}

template<int CTRL, int RM, int BM>
__device__ __forceinline__ float dppmov(float v) {
    return __int_as_float(
        __builtin_amdgcn_update_dpp(0, __float_as_int(v), CTRL, RM, BM, false));
}
// wave64 sum, result in lane 63 (row_shr + row_bcast chain, VALU-only)
__device__ __forceinline__ float wave_sum63(float v) {
    v += dppmov<0x111, 0xf, 0xf>(v);
    v += dppmov<0x112, 0xf, 0xf>(v);
    v += dppmov<0x114, 0xf, 0xf>(v);
    v += dppmov<0x118, 0xf, 0xf>(v);
    v += dppmov<0x142, 0xa, 0xf>(v);
    v += dppmov<0x143, 0xc, 0xf>(v);
    return v;
}

// ============================ Kernel B: pure scan ============================
// 128 WGs x 1 wave. Lane k = chain (batch b, latent triple k). No barriers,
// no cross-lane ops, no LDS. Streams deviatoric state s (f16x4 per step) to ws.
// Projection folded: s0_trial = s0 + g0.dx (3 fma, accumulator-init fold).
__global__ __launch_bounds__(64, 1)
void j2_scan_stream(const float* __restrict__ x,
                    const float* __restrict__ W1,
                    uint4* __restrict__ ws)
{
    const int b = blockIdx.x;
    const int k = threadIdx.x;

    float wr[3][3];
#pragma unroll
    for (int j = 0; j < 3; ++j)
#pragma unroll
        for (int f = 0; f < 3; ++f)
            wr[j][f] = W1[(3 * k + j) * 3 + f];

    float g0[3], g1[3], e2s[3];
#pragma unroll
    for (int f = 0; f < 3; ++f) {
        const float e0 = kC11 * wr[0][f] + kC12 * wr[1][f];
        const float e1 = kC12 * wr[0][f] + kC11 * wr[1][f];
        const float lv = kLam * (wr[0][f] + wr[1][f]);
        g0[f]  = kSq15 * (2.0f * e0 - e1 - lv) * (1.0f / 3.0f);
        g1[f]  = kSq15 * (2.0f * e1 - e0 - lv) * (1.0f / 3.0f);
        e2s[f] = kSq3 * kG * wr[2][f];
    }

    const float* xb = x + (size_t)b * (kS * 3);

    // x window: f[1+3t..3+3t] = x_{s-1}, f[4+3t..6+3t] = x_s  (t = 0..15)
    float fw[52], fn[52];
    fw[0] = fw[1] = fw[2] = fw[3] = 0.0f;
    {
        const float4* s4 = reinterpret_cast<const float4*>(xb);
#pragma unroll
        for (int i = 0; i < 12; ++i) {
            float4 v = s4[i];
            fw[4 + 4 * i] = v.x; fw[5 + 4 * i] = v.y;
            fw[6 + 4 * i] = v.z; fw[7 + 4 * i] = v.w;
        }
    }

    float s0 = 0.f, s1 = 0.f, s2 = 0.f;
    float y = kSy0, c2y = kC2 * kSy0;
    uint4 st;

    for (int p = 0; p < kNBLK; ++p) {
        if (p + 1 < kNBLK) {   // prefetch next window (hidden under 16 steps)
            const float4* s4 =
                reinterpret_cast<const float4*>(xb + 48 * (p + 1) - 4);
#pragma unroll
            for (int i = 0; i < 13; ++i) {
                float4 v = s4[i];
                fn[4 * i]     = v.x; fn[4 * i + 1] = v.y;
                fn[4 * i + 2] = v.z; fn[4 * i + 3] = v.w;
            }
        }
#pragma unroll
        for (int t = 0; t < kT; ++t) {
            const float d0 = fw[4 + 3 * t] - fw[1 + 3 * t];
            const float d1 = fw[5 + 3 * t] - fw[2 + 3 * t];
            const float d2 = fw[6 + 3 * t] - fw[3 + 3 * t];
            const float s0t = fmaf(g0[0], d0, fmaf(g0[1], d1, fmaf(g0[2], d2, s0)));
            const float s1t = fmaf(g1[0], d0, fmaf(g1[1], d1, fmaf(g1[2], d2, s1)));
            const float s2t = fmaf(e2s[0], d0, fmaf(e2s[1], d1, fmaf(e2s[2], d2, s2)));
            const float tt  = s0t + s1t;                     // -szz (trace-free)
            float a = fmaf(s0t, s0t, 1e-12f);
            a = fmaf(s1t, s1t, a);
            a = fmaf(s2t, s2t, a);
            const float q2  = fmaf(tt, tt, a);
            const float rq  = __builtin_amdgcn_rsqf(q2);
            const float fac = fminf(fmaf(c2y, rq, kC3), 1.0f);
            s0 = fac * s0t; s1 = fac * s1t; s2 = fac * s2t;
            const float qv = q2 * rq;
            y = fmaxf(y, fmaf(kC3, qv, c2y));
            c2y = kC2 * y;
            if ((t & 1) == 0) {
                st.x = pk16(s0, s1); st.y = pk16(s2, s2);
            } else {
                st.z = pk16(s0, s1); st.w = pk16(s2, s2);
                ws[((size_t)b * 1024 + p * 8 + (t >> 1)) * 64 + k] = st;
            }
        }
        if (p + 1 < kNBLK) {
#pragma unroll
            for (int i = 0; i < 52; ++i) fw[i] = fn[i];
        }
    }
}

// ========================= Kernel C: output einsum ==========================
// Grid (128 b, 128 tiles) x 64. Lane k reads chain k's s (f16), applies
// softplus(W2) weights + elastic mean-stress term, DPP-reduces across lanes.
__global__ __launch_bounds__(64, 1)
void j2_out_einsum(const float* __restrict__ x,
                   const float* __restrict__ W1,
                   const float* __restrict__ W2,
                   const uint4* __restrict__ ws,
                   float* __restrict__ out)
{
    const int b = blockIdx.x;
    const int tile = blockIdx.y;
    const int k = threadIdx.x;

    float wr[3][3];
#pragma unroll
    for (int j = 0; j < 3; ++j)
#pragma unroll
        for (int f = 0; f < 3; ++f)
            wr[j][f] = W1[(3 * k + j) * 3 + f];
    float mv[3];
#pragma unroll
    for (int f = 0; f < 3; ++f) {
        const float e0 = kC11 * wr[0][f] + kC12 * wr[1][f];
        const float e1 = kC12 * wr[0][f] + kC11 * wr[1][f];
        const float lv = kLam * (wr[0][f] + wr[1][f]);
        mv[f] = (e0 + e1 + lv) * (1.0f / 3.0f);
    }
    float spp[3][3], so[3];
#pragma unroll
    for (int o = 0; o < 3; ++o) {
        const float a0 = __logf(1.0f + __expf(W2[o * kLs + 3 * k + 0]));
        const float a1 = __logf(1.0f + __expf(W2[o * kLs + 3 * k + 1]));
        const float a2 = __logf(1.0f + __expf(W2[o * kLs + 3 * k + 2]));
        spp[o][0] = a0 * kISq15;
        spp[o][1] = a1 * kISq15;
        spp[o][2] = a2 * kISq3;
        so[o] = a0 + a1;
    }

    // x for mean stress (lane-uniform broadcast loads)
    float fx[48];
    {
        const float4* s4 = reinterpret_cast<const float4*>(
            x + (size_t)b * (kS * 3) + tile * 48);
#pragma unroll
        for (int i = 0; i < 12; ++i) {
            float4 v = s4[i];
            fx[4 * i]     = v.x; fx[4 * i + 1] = v.y;
            fx[4 * i + 2] = v.z; fx[4 * i + 3] = v.w;
        }
    }

    float r[48];
#pragma unroll
    for (int j = 0; j < 8; ++j) {
        const uint4 v = ws[((size_t)b * 1024 + tile * 8 + j)* 64 + k];
#pragma unroll
        for (int h = 0; h < 2; ++h) {
            const int t = 2 * j + h;
            const unsigned pa = h ? v.z : v.x;
            const unsigned pb = h ? v.w : v.y;
            const float sx = up16lo(pa);
            const float sy = up16hi(pa);
            const float sv = up16lo(pb);
            const float pm = fmaf(mv[0], fx[3 * t],
                             fmaf(mv[1], fx[3 * t + 1], mv[2] * fx[3 * t + 2]));
#pragma unroll
            for (int o = 0; o < 3; ++o) {
                const float A = fmaf(spp[o][0], sx,
                                fmaf(spp[o][1], sy, spp[o][2] * sv));
                r[3 * t + o] = fmaf(pm, so[o], A);
            }
        }
    }
#pragma unroll
    for (int v = 0; v < 48; ++v) r[v] = wave_sum63(r[v]);
    if (k == 63) {
        float4* o4 = reinterpret_cast<float4*>(
            out + (size_t)b * (kS * 3) + tile * 48);
#pragma unroll
        for (int i = 0; i < 12; ++i)
            o4[i] = make_float4(r[4 * i], r[4 * i + 1],
                                r[4 * i + 2], r[4 * i + 3]);
    }
}

// ================== Fallback: known-good R2 3-wave kernel ===================
__global__ __launch_bounds__(192, 1)
void j2_pc_kernel(const float* __restrict__ x,
                  const float* __restrict__ W1,
                  const float* __restrict__ W2,
                  float* __restrict__ out)
{
    __shared__ float4 ubuf[2][kT][64];
    __shared__ float4 sgbuf[2][kT][64];

    const int b = blockIdx.x;
    const int w = threadIdx.x >> 6;
    const int k = threadIdx.x & 63;

    const float* xb = x + (size_t)b * (kS * 3);
    float* ob = out + (size_t)b * (kS * 3);

    float e0[3], e1[3], e2[3], lv[3], sp[3][3];
    if (w != 0) {
        float wr[3][3];
#pragma unroll
        for (int j = 0; j < 3; ++j)
#pragma unroll
            for (int f = 0; f < 3; ++f)
                wr[j][f] = W1[(3 * k + j) * 3 + f];
#pragma unroll
        for (int f = 0; f < 3; ++f) {
            e0[f] = kC11 * wr[0][f] + kC12 * wr[1][f];
            e1[f] = kC12 * wr[0][f] + kC11 * wr[1][f];
            e2[f] = kG * wr[2][f];
            lv[f] = kLam * (wr[0][f] + wr[1][f]);
        }
#pragma unroll
        for (int o = 0; o < 3; ++o)
#pragma unroll
            for (int j = 0; j < 3; ++j) {
                float v = W2[o * kLs + 3 * k + j];
                sp[o][j] = log1pf(expf(v));
            }
    }

    float sg0 = 0.f, sg1 = 0.f, sg2 = 0.f, szz = 0.f;
    float y = kSy0;
    const int tlo = (w == 2) ? 8 : 0;
    constexpr float kInv3GH = 1.0f / (3.0f * kG + kH);
    constexpr float k3G = 3.0f * kG;

    for (int phase = 0; phase <= kNBLK + 1; ++phase) {
        if (w == 0) {
            if (phase >= 1 && phase <= kNBLK) {
                const int blk = phase - 1, pb = blk & 1;
                float4 u[kT];
#pragma unroll
                for (int t = 0; t < kT; ++t) u[t] = ubuf[pb][t][k];
#pragma unroll
                for (int t = 0; t < kT; ++t) {
                    const float t0 = sg0 + u[t].x;
                    const float t1 = sg1 + u[t].y;
                    const float t2 = sg2 + u[t].z;
                    const float tz = szz + u[t].w;
                    const float pm  = (t0 + t1 + tz) * (1.0f / 3.0f);
                    const float dxx = t0 - pm, dyy = t1 - pm, dzz = tz - pm;
                    const float sa  = fmaf(dxx, dxx, dyy * dyy);
                    const float sb  = fmaf(dzz, dzz, (2.0f * t2) * t2);
                    const float q2  = fmaf(1.5f, sa + sb, 1e-12f);
                    const float qq  = __builtin_amdgcn_sqrtf(q2);
                    const float rq  = __builtin_amdgcn_rcpf(qq);
                    const float f   = qq - y;
                    const float dg  = (f > 0.0f) ? f * kInv3GH : 0.0f;
                    y = fmaf(kH, dg, y);
                    const float fac = fmaf(-(k3G * dg), rq, 1.0f);
                    sg0 = fmaf(fac, dxx, pm);
                    sg1 = fmaf(fac, dyy, pm);
                    sg2 = fac * t2;
                    szz = fmaf(fac, dzz, pm);
                    sgbuf[pb][t][k] = make_float4(sg0, sg1, sg2, 0.f);
                }
            }
        } else {
            if (phase < kNBLK) {
                const int p = phase, pb = p & 1;
                float xv[28];
                if (w == 1) {
                    if (p == 0) {
                        xv[0] = xv[1] = xv[2] = xv[3] = 0.f;
                        const float4* s4 = reinterpret_cast<const float4*>(xb);
#pragma unroll
                        for (int i = 0; i < 6; ++i) {
                            float4 v = s4[i];
                            xv[4 + 4 * i] = v.x; xv[5 + 4 * i] = v.y;
                            xv[6 + 4 * i] = v.z; xv[7 + 4 * i] = v.w;
                        }
                    } else {
                        const float4* s4 =
                            reinterpret_cast<const float4*>(xb + p * 48 - 4);
#pragma unroll
                        for (int i = 0; i < 7; ++i) {
                            float4 v = s4[i];
                            xv[4 * i]     = v.x; xv[4 * i + 1] = v.y;
                            xv[4 * i + 2] = v.z; xv[4 * i + 3] = v.w;
                        }
                    }
                } else {
                    const float4* s4 =
                        reinterpret_cast<const float4*>(xb + p * 48 + 20);
#pragma unroll
                    for (int i = 0; i < 7; ++i) {
                        float4 v = s4[i];
                        xv[4 * i]     = v.x; xv[4 * i + 1] = v.y;
                        xv[4 * i + 2] = v.z; xv[4 * i + 3] = v.w;
                    }
                }
                const int tbase = (w == 2) ? 8 : 0;
#pragma unroll
                for (int t = 0; t < 8; ++t) {
                    const float dx0 = xv[3 * t + 4] - xv[3 * t + 1];
                    const float dx1 = xv[3 * t + 5] - xv[3 * t + 2];
                    const float dx2 = xv[3 * t + 6] - xv[3 * t + 3];
                    float4 u;
                    u.x = fmaf(e0[0], dx0, fmaf(e0[1], dx1, e0[2] * dx2));
                    u.y = fmaf(e1[0], dx0, fmaf(e1[1], dx1, e1[2] * dx2));
                    u.z = fmaf(e2[0], dx0, fmaf(e2[1], dx1, e2[2] * dx2));
                    u.w = fmaf(lv[0], dx0, fmaf(lv[1], dx1, lv[2] * dx2));
                    ubuf[pb][tbase + t][k] = u;
                }
            }
            if (phase >= 2) {
                const int q = phase - 2, qb = q & 1;
                const int tbase = tlo;
                float r[24];
#pragma unroll
                for (int t = 0; t < 8; ++t) {
                    float4 s = sgbuf[qb][tbase + t][k];
                    r[3 * t]     = fmaf(sp[0][0], s.x, fmaf(sp[0][1], s.y, sp[0][2] * s.z));
                    r[3 * t + 1] = fmaf(sp[1][0], s.x, fmaf(sp[1][1], s.y, sp[1][2] * s.z));
                    r[3 * t + 2] = fmaf(sp[2][0], s.x, fmaf(sp[2][1], s.y, sp[2][2] * s.z));
                }
#pragma unroll
                for (int v = 0; v < 24; ++v) r[v] = wave_sum63(r[v]);
                if (k == 63) {
                    float4* o4 = reinterpret_cast<float4*>(ob + q * 48 + tbase * 3);
#pragma unroll
                    for (int i = 0; i < 6; ++i)
                        o4[i] = make_float4(r[4 * i], r[4 * i + 1],
                                            r[4 * i + 2], r[4 * i + 3]);
                }
            }
        }
        __syncthreads();
    }
}

extern "C" void kernel_launch(void* const* d_in, const int* in_sizes, int n_in,
                              void* d_out, int out_size, void* d_ws, size_t ws_size,
                              hipStream_t stream) {
    const float* x  = (const float*)d_in[0];   // (128, 2048, 3)
    const float* W1 = (const float*)d_in[1];   // (192, 3)
    const float* W2 = (const float*)d_in[2];   // (3, 192)
    float* out = (float*)d_out;                // (128, 2048, 3)

    const size_t need = (size_t)128 * 1024 * 64 * sizeof(uint4);  // 128 MiB
    if (ws_size >= need) {
        uint4* ws = (uint4*)d_ws;
        j2_scan_stream<<<dim3(128), dim3(64), 0, stream>>>(x, W1, ws);
        j2_out_einsum<<<dim3(128, 128), dim3(64), 0, stream>>>(x, W1, W2, ws, out);
    } else {
        j2_pc_kernel<<<dim3(128), dim3(192), 0, stream>>>(x, W1, W2, out);
    }
}